// Round 7
// baseline (204.638 us; speedup 1.0000x reference)
//
#include <hip/hip_runtime.h>
#include <hip/hip_bf16.h>

#define NN 8192
#define NE 262144
#define CAP 96

typedef __attribute__((ext_vector_type(8))) __bf16 bf16x8;
typedef __attribute__((ext_vector_type(4))) float f32x4;

__device__ __forceinline__ ushort f2b(float v) {
    __hip_bfloat16 b = __float2bfloat16(v);
    return *reinterpret_cast<ushort*>(&b);
}
__device__ __forceinline__ uint pack2(float lo, float hi) {
    return (uint)f2b(lo) | ((uint)f2b(hi) << 16);
}

// ---------------------------------------------------------------------------
// prep: zero cnt (blocks 0..31) + 9 weight transposes ([K][N] f32 -> [N][K] bf16)
// ---------------------------------------------------------------------------
struct PrepArgs {
    int* cnt;
    const float* w[9]; ushort* wt[9];
};

__global__ __launch_bounds__(256) void prep_k(PrepArgs a) {
    const int bid = blockIdx.x, tid = threadIdx.x;
    if (bid < 32) { a.cnt[bid * 256 + tid] = 0; return; }
    int id = (bid - 32) * 256 + tid;     // weight transpose, 376832 total
    if (id >= 376832) return;
    const int cum[10] = {0, 16384, 49152, 81920, 147456, 212992, 278528, 344064, 360448, 376832};
    const int KK[9] = {128, 128, 128, 256, 256, 256, 256, 256, 256};
    const int LN[9] = {7, 8, 8, 8, 8, 8, 8, 6, 6};   // log2(N)
    int m = 0;
#pragma unroll
    for (int t = 1; t < 9; ++t) m += (id >= cum[t]);
    int local = id - cum[m];
    int K = KK[m], ln = LN[m];
    int k = local >> ln, n = local & ((1 << ln) - 1);
    a.wt[m][n * K + k] = f2b(a.w[m][local]);
}

// ---------------------------------------------------------------------------
// scatter (blocks 0..1023)  ||  pool1 GEMM (blocks 1024..1279)
// pool1: P1 = relu(feat @ Wp1 + bp1), feat f32 converted on the fly.
// per block: 32-row stripe, N=128, K=128. 4 waves (2x2), wave tile 16x64.
// ---------------------------------------------------------------------------
__global__ __launch_bounds__(256) void scat_pool1_k(
    const int* __restrict__ src, const int* __restrict__ dst,
    const float* __restrict__ ew, int* __restrict__ cnt, uint2* __restrict__ slots,
    const float* __restrict__ feat, const ushort* __restrict__ WpT,
    const float* __restrict__ bp, ushort* __restrict__ Pout) {
    const int tid = threadIdx.x;
    if (blockIdx.x < NE / 256) {
        int e = blockIdx.x * 256 + tid;
        int d = dst[e];
        int p = atomicAdd(&cnt[d], 1);
        if (p < CAP) slots[(size_t)d * CAP + p] = make_uint2((uint)src[e], __float_as_uint(ew[e]));
        return;
    }
    __shared__ __align__(16) ushort As[32 * 72];
    __shared__ __align__(16) ushort Bs[128 * 72];
    const int m0 = (blockIdx.x - NE / 256) * 32;
    const int lane = tid & 63, wave = tid >> 6;
    const int r16 = lane & 15, kb = lane >> 4;
    const int wm = (wave >> 1) * 16, wn = (wave & 1) * 64;

    f32x4 acc[4];
#pragma unroll
    for (int j = 0; j < 4; ++j) acc[j] = (f32x4)(0.f);

#pragma unroll
    for (int k0 = 0; k0 < 128; k0 += 64) {
#pragma unroll
        for (int rep = 0; rep < 2; ++rep) {       // A: 32 rows x 64 f32 -> bf16
            int id = rep * 256 + tid;
            int row = id >> 4, c = id & 15;
            float4 f = *(const float4*)&feat[(size_t)(m0 + row) * 128 + k0 + c * 4];
            uint2 o; o.x = pack2(f.x, f.y); o.y = pack2(f.z, f.w);
            *(uint2*)&As[row * 72 + c * 4] = o;
        }
#pragma unroll
        for (int rep = 0; rep < 4; ++rep) {       // B: 128 rows x 64
            int id = rep * 256 + tid;
            int row = id >> 3, c = id & 7;
            *(bf16x8*)&Bs[row * 72 + c * 8] = *(const bf16x8*)&WpT[(size_t)row * 128 + k0 + c * 8];
        }
        __syncthreads();
#pragma unroll
        for (int kc = 0; kc < 2; ++kc) {
            bf16x8 a = *(const bf16x8*)&As[(wm + r16) * 72 + kc * 32 + kb * 8];
#pragma unroll
            for (int j = 0; j < 4; ++j) {
                bf16x8 b = *(const bf16x8*)&Bs[(wn + 16 * j + r16) * 72 + kc * 32 + kb * 8];
                acc[j] = __builtin_amdgcn_mfma_f32_16x16x32_bf16(a, b, acc[j], 0, 0, 0);
            }
        }
        __syncthreads();
    }
#pragma unroll
    for (int j = 0; j < 4; ++j) {
        int col = wn + 16 * j + r16;
        float bv = bp[col];
#pragma unroll
        for (int rr = 0; rr < 4; ++rr) {
            int rl = wm + kb * 4 + rr;
            Pout[(size_t)(m0 + rl) * 128 + col] = f2b(fmaxf(acc[j][rr] + bv, 0.f));
        }
    }
}

// ---------------------------------------------------------------------------
// fused layer: per 32-row stripe block:
//   1) segmax over P_in (gather)        -> G in LDS
//   2) X = relu(A1 @ WsT^T + G @ WnT^T + b)  (full N=DOUT per block)
//      -> write X (bf16 global), keep in LDS as T
//   3) if POOL: P_out = relu(T @ WpT^T + bp)
// LAST: X -> Fout (f32) + Xout (bf16 hdb), no pool.
// ---------------------------------------------------------------------------
template <int DIN, int DOUT, bool A1F32, bool POOL, bool LAST>
__global__ __launch_bounds__(256) void layer_k(
    const void* __restrict__ A1v, const ushort* __restrict__ Pin,
    const int* __restrict__ cnt, const uint2* __restrict__ slots,
    const ushort* __restrict__ WsT, const ushort* __restrict__ WnT,
    const float* __restrict__ bias,
    const ushort* __restrict__ WpT, const float* __restrict__ biasp,
    ushort* __restrict__ Xout, float* __restrict__ Fout, ushort* __restrict__ Pout) {
    constexpr int SG = DIN + 8, ST = DOUT + 8, NJ = DOUT / 32, FPL = DIN / 64;
    __shared__ __align__(16) ushort G[32 * SG];
    __shared__ __align__(16) ushort T[32 * ST];
    __shared__ __align__(16) ushort As[32 * 72];
    __shared__ __align__(16) ushort Bs[DOUT * 72];

    const int tid = threadIdx.x, lane = tid & 63, wave = tid >> 6;
    const int r16 = lane & 15, kb = lane >> 4;
    const int wm = (wave >> 1) * 16, wn = (wave & 1) * (DOUT / 2);
    const int m0 = blockIdx.x * 32;

    // ---- 1) segment max -> G  (each wave: 8 nodes, full row per wave)
    {
        const int f0 = lane * FPL;
        for (int r = 0; r < 8; ++r) {
            int nl = wave * 8 + r, node = m0 + nl;
            int n = cnt[node]; if (n > CAP) n = CAP;
            const uint2* sl = &slots[(size_t)node * CAP];
            float mx[FPL];
#pragma unroll
            for (int i = 0; i < FPL; ++i) mx[i] = 0.f;
            auto upd = [&](uint s, float w) {
                const uint* hp = (const uint*)&Pin[(size_t)s * DIN + f0];
#pragma unroll
                for (int c = 0; c < FPL / 2; ++c) {
                    uint u = hp[c];
                    float lo = __uint_as_float(u << 16);
                    float hi = __uint_as_float(u & 0xffff0000u);
                    mx[2 * c] = fmaxf(mx[2 * c], lo * w);
                    mx[2 * c + 1] = fmaxf(mx[2 * c + 1], hi * w);
                }
            };
            int e = 0;
            for (; e + 8 <= n; e += 8) {
                uint2 d[8];
#pragma unroll
                for (int t = 0; t < 8; ++t) d[t] = sl[e + t];
#pragma unroll
                for (int t = 0; t < 8; ++t) upd(d[t].x, __uint_as_float(d[t].y));
            }
            for (; e < n; ++e) { uint2 d = sl[e]; upd(d.x, __uint_as_float(d.y)); }
            uint* gp = (uint*)&G[nl * SG + f0];
#pragma unroll
            for (int c = 0; c < FPL / 2; ++c) gp[c] = pack2(mx[2 * c], mx[2 * c + 1]);
        }
    }
    __syncthreads();

    // ---- 2) dual GEMM
    f32x4 acc[NJ];
#pragma unroll
    for (int j = 0; j < NJ; ++j) acc[j] = (f32x4)(0.f);

    // pass 1: self
    for (int k0 = 0; k0 < DIN; k0 += 64) {
        if constexpr (A1F32) {
            const float* A1 = (const float*)A1v;
#pragma unroll
            for (int rep = 0; rep < 2; ++rep) {
                int id = rep * 256 + tid;
                int row = id >> 4, c = id & 15;
                float4 f = *(const float4*)&A1[(size_t)(m0 + row) * DIN + k0 + c * 4];
                uint2 o; o.x = pack2(f.x, f.y); o.y = pack2(f.z, f.w);
                *(uint2*)&As[row * 72 + c * 4] = o;
            }
        } else {
            const ushort* A1 = (const ushort*)A1v;
            int row = tid >> 3, c = tid & 7;
            *(bf16x8*)&As[row * 72 + c * 8] = *(const bf16x8*)&A1[(size_t)(m0 + row) * DIN + k0 + c * 8];
        }
#pragma unroll
        for (int rep = 0; rep < DOUT / 32; ++rep) {
            int id = rep * 256 + tid;
            int row = id >> 3, c = id & 7;
            *(bf16x8*)&Bs[row * 72 + c * 8] = *(const bf16x8*)&WsT[(size_t)row * DIN + k0 + c * 8];
        }
        __syncthreads();
#pragma unroll
        for (int kc = 0; kc < 2; ++kc) {
            bf16x8 a = *(const bf16x8*)&As[(wm + r16) * 72 + kc * 32 + kb * 8];
#pragma unroll
            for (int j = 0; j < NJ; ++j) {
                bf16x8 b = *(const bf16x8*)&Bs[(wn + 16 * j + r16) * 72 + kc * 32 + kb * 8];
                acc[j] = __builtin_amdgcn_mfma_f32_16x16x32_bf16(a, b, acc[j], 0, 0, 0);
            }
        }
        __syncthreads();
    }
    // pass 2: neigh (A from LDS G)
    for (int k0 = 0; k0 < DIN; k0 += 64) {
#pragma unroll
        for (int rep = 0; rep < DOUT / 32; ++rep) {
            int id = rep * 256 + tid;
            int row = id >> 3, c = id & 7;
            *(bf16x8*)&Bs[row * 72 + c * 8] = *(const bf16x8*)&WnT[(size_t)row * DIN + k0 + c * 8];
        }
        __syncthreads();
#pragma unroll
        for (int kc = 0; kc < 2; ++kc) {
            bf16x8 a = *(const bf16x8*)&G[(wm + r16) * SG + k0 + kc * 32 + kb * 8];
#pragma unroll
            for (int j = 0; j < NJ; ++j) {
                bf16x8 b = *(const bf16x8*)&Bs[(wn + 16 * j + r16) * 72 + kc * 32 + kb * 8];
                acc[j] = __builtin_amdgcn_mfma_f32_16x16x32_bf16(a, b, acc[j], 0, 0, 0);
            }
        }
        __syncthreads();
    }

    // epilogue: X (+T for pool)
#pragma unroll
    for (int j = 0; j < NJ; ++j) {
        int col = wn + 16 * j + r16;
        float bv = bias[col];
#pragma unroll
        for (int rr = 0; rr < 4; ++rr) {
            int rl = wm + kb * 4 + rr;
            float v = fmaxf(acc[j][rr] + bv, 0.f);
            if constexpr (LAST) {
                Fout[(size_t)(m0 + rl) * DOUT + col] = v;
                Xout[(size_t)(m0 + rl) * DOUT + col] = f2b(v);
            } else {
                T[rl * ST + col] = f2b(v);
                Xout[(size_t)(m0 + rl) * DOUT + col] = f2b(v);
            }
        }
    }

    // ---- 3) next layer's pool GEMM from T
    if constexpr (POOL) {
        __syncthreads();
        f32x4 acc2[NJ];
#pragma unroll
        for (int j = 0; j < NJ; ++j) acc2[j] = (f32x4)(0.f);
        for (int k0 = 0; k0 < DOUT; k0 += 64) {
#pragma unroll
            for (int rep = 0; rep < DOUT / 32; ++rep) {
                int id = rep * 256 + tid;
                int row = id >> 3, c = id & 7;
                *(bf16x8*)&Bs[row * 72 + c * 8] = *(const bf16x8*)&WpT[(size_t)row * DOUT + k0 + c * 8];
            }
            __syncthreads();
#pragma unroll
            for (int kc = 0; kc < 2; ++kc) {
                bf16x8 a = *(const bf16x8*)&T[(wm + r16) * ST + k0 + kc * 32 + kb * 8];
#pragma unroll
                for (int j = 0; j < NJ; ++j) {
                    bf16x8 b = *(const bf16x8*)&Bs[(wn + 16 * j + r16) * 72 + kc * 32 + kb * 8];
                    acc2[j] = __builtin_amdgcn_mfma_f32_16x16x32_bf16(a, b, acc2[j], 0, 0, 0);
                }
            }
            __syncthreads();
        }
#pragma unroll
        for (int j = 0; j < NJ; ++j) {
            int col = wn + 16 * j + r16;
            float bv = biasp[col];
#pragma unroll
            for (int rr = 0; rr < 4; ++rr) {
                int rl = wm + kb * 4 + rr;
                Pout[(size_t)(m0 + rl) * DOUT + col] = f2b(fmaxf(acc2[j][rr] + bv, 0.f));
            }
        }
    }
}

// ---------------------------------------------------------------------------
// adj = H @ H^T, H [8192][64] bf16, C fp32. 128x128 tile, K=64 single stage.
// ---------------------------------------------------------------------------
__global__ __launch_bounds__(256) void aat_k(const ushort* __restrict__ H,
                                             float* __restrict__ C) {
    __shared__ __align__(16) ushort As[128 * 72];
    __shared__ __align__(16) ushort Bs[128 * 72];
    int tid = threadIdx.x, lane = tid & 63, wave = tid >> 6;
    int wm = (wave >> 1) * 64, wn = (wave & 1) * 64;
    int r16 = lane & 15, kb = lane >> 4;
    int m0 = blockIdx.y * 128, n0 = blockIdx.x * 128;

#pragma unroll
    for (int rep = 0; rep < 4; ++rep) {
        int id = rep * 256 + tid;
        int row = id >> 3, c = id & 7;
        *(bf16x8*)&As[row * 72 + c * 8] = *(const bf16x8*)&H[(size_t)(m0 + row) * 64 + c * 8];
        *(bf16x8*)&Bs[row * 72 + c * 8] = *(const bf16x8*)&H[(size_t)(n0 + row) * 64 + c * 8];
    }
    __syncthreads();

    f32x4 acc[4][4];
#pragma unroll
    for (int i = 0; i < 4; ++i)
#pragma unroll
        for (int j = 0; j < 4; ++j) acc[i][j] = (f32x4)(0.f);

#pragma unroll
    for (int kc = 0; kc < 2; ++kc) {
        bf16x8 a[4], b[4];
#pragma unroll
        for (int i = 0; i < 4; ++i)
            a[i] = *(const bf16x8*)&As[(wm + 16 * i + r16) * 72 + kc * 32 + kb * 8];
#pragma unroll
        for (int j = 0; j < 4; ++j)
            b[j] = *(const bf16x8*)&Bs[(wn + 16 * j + r16) * 72 + kc * 32 + kb * 8];
#pragma unroll
        for (int i = 0; i < 4; ++i)
#pragma unroll
            for (int j = 0; j < 4; ++j)
                acc[i][j] = __builtin_amdgcn_mfma_f32_16x16x32_bf16(a[i], b[j], acc[i][j], 0, 0, 0);
    }

#pragma unroll
    for (int i = 0; i < 4; ++i) {
#pragma unroll
        for (int j = 0; j < 4; ++j) {
            int col = n0 + wn + 16 * j + r16;
#pragma unroll
            for (int r = 0; r < 4; ++r) {
                size_t row = m0 + wm + 16 * i + kb * 4 + r;
                C[row * NN + col] = acc[i][j][r];
            }
        }
    }
}

// ---------------------------------------------------------------------------
extern "C" void kernel_launch(void* const* d_in, const int* in_sizes, int n_in,
                              void* d_out, int out_size, void* d_ws, size_t ws_size,
                              hipStream_t stream) {
    const float* feat = (const float*)d_in[0];
    const int* src = (const int*)d_in[1];
    const int* dst = (const int*)d_in[2];
    const float* ew = (const float*)d_in[3];
    const float* Wp1 = (const float*)d_in[5];
    const float* bp1 = (const float*)d_in[6];
    const float* Ws1 = (const float*)d_in[7];
    const float* Wn1 = (const float*)d_in[8];
    const float* b1  = (const float*)d_in[9];
    const float* Wp2 = (const float*)d_in[10];
    const float* bp2 = (const float*)d_in[11];
    const float* Ws2 = (const float*)d_in[12];
    const float* Wn2 = (const float*)d_in[13];
    const float* b2  = (const float*)d_in[14];
    const float* Wp3 = (const float*)d_in[15];
    const float* bp3 = (const float*)d_in[16];
    const float* Ws3 = (const float*)d_in[17];
    const float* Wn3 = (const float*)d_in[18];
    const float* b3  = (const float*)d_in[19];

    float* out = (float*)d_out;          // hd fp32 [8192][64]
    float* adj = out + (size_t)NN * 64;  // adj fp32 [8192][8192]

    char* ws = (char*)d_ws;
    int* cnt      = (int*)(ws + 0x0);          // 32 KB
    uint2* slots  = (uint2*)(ws + 0x10000);    // 6 MB
    ushort* Wp1T = (ushort*)(ws + 0x620000);
    ushort* Ws1T = (ushort*)(ws + 0x628000);
    ushort* Wn1T = (ushort*)(ws + 0x638000);
    ushort* Wp2T = (ushort*)(ws + 0x648000);
    ushort* Ws2T = (ushort*)(ws + 0x668000);
    ushort* Wn2T = (ushort*)(ws + 0x688000);
    ushort* Wp3T = (ushort*)(ws + 0x6A8000);
    ushort* Ws3T = (ushort*)(ws + 0x6C8000);
    ushort* Wn3T = (ushort*)(ws + 0x6D0000);
    ushort* P1 = (ushort*)(ws + 0x700000);     // [N][128] bf16
    ushort* P2 = (ushort*)(ws + 0x900000);     // [N][256] bf16
    ushort* P3 = (ushort*)(ws + 0xD00000);     // [N][256] bf16
    ushort* X  = (ushort*)(ws + 0x1100000);    // [N][256] bf16
    ushort* Y  = (ushort*)(ws + 0x1500000);    // [N][256] bf16
    ushort* hdb = (ushort*)(ws + 0x1900000);   // [N][64] bf16

    // prep: zero cnt + transpose weights
    PrepArgs pa;
    pa.cnt = cnt;
    const float* wsrc[9] = {Wp1, Ws1, Wn1, Wp2, Ws2, Wn2, Wp3, Ws3, Wn3};
    ushort* wdst[9] = {Wp1T, Ws1T, Wn1T, Wp2T, Ws2T, Wn2T, Wp3T, Ws3T, Wn3T};
    for (int i = 0; i < 9; ++i) { pa.w[i] = wsrc[i]; pa.wt[i] = wdst[i]; }
    prep_k<<<32 + 1472, 256, 0, stream>>>(pa);

    // scatter || pool1
    scat_pool1_k<<<NE / 256 + NN / 32, 256, 0, stream>>>(
        src, dst, ew, cnt, slots, feat, Wp1T, bp1, P1);

    // fused layers
    layer_k<128, 256, true, true, false><<<NN / 32, 256, 0, stream>>>(
        feat, P1, cnt, slots, Ws1T, Wn1T, b1, Wp2T, bp2, X, nullptr, P2);
    layer_k<256, 256, false, true, false><<<NN / 32, 256, 0, stream>>>(
        X, P2, cnt, slots, Ws2T, Wn2T, b2, Wp3T, bp3, Y, nullptr, P3);
    layer_k<256, 64, false, false, true><<<NN / 32, 256, 0, stream>>>(
        Y, P3, cnt, slots, Ws3T, Wn3T, b3, nullptr, nullptr, hdb, out, nullptr);

    // adj = hd @ hd^T
    aat_k<<<dim3(NN / 128, NN / 128), 256, 0, stream>>>(hdb, adj);
}

// Round 8
// 165.291 us; speedup vs baseline: 1.2380x; 1.2380x over previous
//
#include <hip/hip_runtime.h>
#include <hip/hip_bf16.h>

#define NN 8192
#define NE 262144
#define CAP 96

typedef __attribute__((ext_vector_type(8))) __bf16 bf16x8;
typedef __attribute__((ext_vector_type(4))) float f32x4;

__device__ __forceinline__ ushort f2b(float v) {
    __hip_bfloat16 b = __float2bfloat16(v);
    return *reinterpret_cast<ushort*>(&b);
}
__device__ __forceinline__ uint pack2(float lo, float hi) {
    return (uint)f2b(lo) | ((uint)f2b(hi) << 16);
}
__device__ __forceinline__ float b2f(ushort u) {
    return __uint_as_float(((uint)u) << 16);
}

// ---------------------------------------------------------------------------
// prep+scatter: blocks 0..1023 scatter edges into padded slots; 1024+ transpose
// 9 weights ([K][N] f32 -> [N][K] bf16). cnt must be zeroed (memset) before.
// ---------------------------------------------------------------------------
struct PrepArgs {
    const int* src; const int* dst; const float* ew;
    int* cnt; uint2* slots;
    const float* w[9]; ushort* wt[9];
};

__global__ __launch_bounds__(256) void prep_scatter_k(PrepArgs a) {
    const int bid = blockIdx.x, tid = threadIdx.x;
    if (bid < 1024) {
        int e = bid * 256 + tid;
        int d = a.dst[e];
        int p = atomicAdd(&a.cnt[d], 1);
        if (p < CAP) a.slots[(size_t)d * CAP + p] = make_uint2((uint)a.src[e], __float_as_uint(a.ew[e]));
        return;
    }
    int id = (bid - 1024) * 256 + tid;    // weight transpose, 376832 total
    if (id >= 376832) return;
    const int cum[10] = {0, 16384, 49152, 81920, 147456, 212992, 278528, 344064, 360448, 376832};
    const int KK[9] = {128, 128, 128, 256, 256, 256, 256, 256, 256};
    const int LN[9] = {7, 8, 8, 8, 8, 8, 8, 6, 6};   // log2(N)
    int m = 0;
#pragma unroll
    for (int t = 1; t < 9; ++t) m += (id >= cum[t]);
    int local = id - cum[m];
    int K = KK[m], ln = LN[m];
    int k = local >> ln, n = local & ((1 << ln) - 1);
    a.wt[m][n * K + k] = f2b(a.w[m][local]);
}

// ---------------------------------------------------------------------------
// bf16 MFMA GEMM, BK=128: C = act(A @ BT^T + addend)
// A [8192][K] (f32 converted on the fly if A1F32, else bf16), BT [N][K] bf16.
// 4 waves (2x2), wave tile (BM/2)x(BN/2). addend = bias[col] or bf16 cin[row][col].
// OUTMODE: 0 = bf16 only, 1 = f32 only, 2 = both.
// ---------------------------------------------------------------------------
#define AWK 136   // 128 + 8 pad (ushorts)

template <int BM, int BN, bool A1F32, bool RELU, int OUTMODE, bool ADDC>
__global__ __launch_bounds__(256, 4) void gemm_k(
    const void* __restrict__ Av, const ushort* __restrict__ BT, int K,
    const float* __restrict__ bias, const ushort* __restrict__ cin,
    float* __restrict__ Cf, ushort* __restrict__ Cb, int N) {
    constexpr int MI = BM / 32, NJ = BN / 32;
    __shared__ __align__(16) ushort As[BM * AWK];
    __shared__ __align__(16) ushort Bs[BN * AWK];

    const int tid = threadIdx.x, lane = tid & 63, wave = tid >> 6;
    const int wm = (wave >> 1) * (BM / 2), wn = (wave & 1) * (BN / 2);
    const int r16 = lane & 15, kb = lane >> 4;
    const int m0 = blockIdx.y * BM, n0 = blockIdx.x * BN;

    f32x4 acc[MI][NJ];
#pragma unroll
    for (int i = 0; i < MI; ++i)
#pragma unroll
        for (int j = 0; j < NJ; ++j) acc[i][j] = (f32x4)(0.f);

    for (int k0 = 0; k0 < K; k0 += 128) {
        if constexpr (A1F32) {
            const float* A = (const float*)Av;
#pragma unroll
            for (int rep = 0; rep < BM / 8; ++rep) {
                int id = rep * 256 + tid;
                int row = id >> 5, c = id & 31;
                float4 f = *(const float4*)&A[(size_t)(m0 + row) * K + k0 + c * 4];
                uint2 o; o.x = pack2(f.x, f.y); o.y = pack2(f.z, f.w);
                *(uint2*)&As[row * AWK + c * 4] = o;
            }
        } else {
            const ushort* A = (const ushort*)Av;
#pragma unroll
            for (int rep = 0; rep < BM / 16; ++rep) {
                int id = rep * 256 + tid;
                int row = id >> 4, c = id & 15;
                *(bf16x8*)&As[row * AWK + c * 8] =
                    *(const bf16x8*)&A[(size_t)(m0 + row) * K + k0 + c * 8];
            }
        }
#pragma unroll
        for (int rep = 0; rep < BN / 16; ++rep) {
            int id = rep * 256 + tid;
            int row = id >> 4, c = id & 15;
            *(bf16x8*)&Bs[row * AWK + c * 8] =
                *(const bf16x8*)&BT[(size_t)(n0 + row) * K + k0 + c * 8];
        }
        __syncthreads();
#pragma unroll
        for (int kc = 0; kc < 4; ++kc) {
            bf16x8 a[MI], b[NJ];
#pragma unroll
            for (int i = 0; i < MI; ++i)
                a[i] = *(const bf16x8*)&As[(wm + 16 * i + r16) * AWK + kc * 32 + kb * 8];
#pragma unroll
            for (int j = 0; j < NJ; ++j)
                b[j] = *(const bf16x8*)&Bs[(wn + 16 * j + r16) * AWK + kc * 32 + kb * 8];
#pragma unroll
            for (int i = 0; i < MI; ++i)
#pragma unroll
                for (int j = 0; j < NJ; ++j)
                    acc[i][j] = __builtin_amdgcn_mfma_f32_16x16x32_bf16(a[i], b[j], acc[i][j], 0, 0, 0);
        }
        __syncthreads();
    }

#pragma unroll
    for (int i = 0; i < MI; ++i) {
#pragma unroll
        for (int j = 0; j < NJ; ++j) {
            int col = n0 + wn + 16 * j + r16;
            float bv = ADDC ? 0.f : bias[col];
#pragma unroll
            for (int r = 0; r < 4; ++r) {
                int row = m0 + wm + 16 * i + kb * 4 + r;
                float v = acc[i][j][r];
                if constexpr (ADDC) v += b2f(cin[(size_t)row * N + col]);
                else v += bv;
                if (RELU) v = fmaxf(v, 0.f);
                if (OUTMODE != 0) Cf[(size_t)row * N + col] = v;
                if (OUTMODE != 1) Cb[(size_t)row * N + col] = f2b(v);
            }
        }
    }
}

// ---------------------------------------------------------------------------
// seg || self: blocks 0..2047 = segmax (1 wave/node); blocks 2048+ = self-GEMM
// Cself = A @ WsT^T + bias (bf16 out, no relu). BK=128.
// ---------------------------------------------------------------------------
template <int DIN, int DOUT, bool A1F32>
__global__ __launch_bounds__(256, 4) void seg_self_k(
    const ushort* __restrict__ Pin, const int* __restrict__ cnt,
    const uint2* __restrict__ slots, ushort* __restrict__ G,
    const void* __restrict__ Av, const ushort* __restrict__ WsT,
    const float* __restrict__ bias, ushort* __restrict__ Cself) {
    constexpr int BM = (DOUT == 64) ? 32 : 64;
    constexpr int NBX = DOUT / 64;
    constexpr int MI = BM / 32, NJ = 2;
    __shared__ __align__(16) ushort As[BM * AWK];
    __shared__ __align__(16) ushort Bs[64 * AWK];

    const int tid = threadIdx.x, lane = tid & 63, wave = tid >> 6;

    if (blockIdx.x < 2048) {
        // ---- segmax
        constexpr int FPL = DIN / 64;
        int node = blockIdx.x * 4 + wave;
        int f0 = lane * FPL;
        int n = cnt[node]; if (n > CAP) n = CAP;
        const uint2* sl = &slots[(size_t)node * CAP];
        float mx[FPL];
#pragma unroll
        for (int i = 0; i < FPL; ++i) mx[i] = 0.f;
        auto upd = [&](uint s, float w) {
            const uint* hp = (const uint*)&Pin[(size_t)s * DIN + f0];
#pragma unroll
            for (int c = 0; c < FPL / 2; ++c) {
                uint u = hp[c];
                float lo = __uint_as_float(u << 16);
                float hi = __uint_as_float(u & 0xffff0000u);
                mx[2 * c] = fmaxf(mx[2 * c], lo * w);
                mx[2 * c + 1] = fmaxf(mx[2 * c + 1], hi * w);
            }
        };
        int e = 0;
        for (; e + 8 <= n; e += 8) {
            uint2 d[8];
#pragma unroll
            for (int t = 0; t < 8; ++t) d[t] = sl[e + t];
#pragma unroll
            for (int t = 0; t < 8; ++t) upd(d[t].x, __uint_as_float(d[t].y));
        }
        for (; e < n; ++e) { uint2 d = sl[e]; upd(d.x, __uint_as_float(d.y)); }
        uint* gp = (uint*)&G[(size_t)node * DIN + f0];
#pragma unroll
        for (int c = 0; c < FPL / 2; ++c) gp[c] = pack2(mx[2 * c], mx[2 * c + 1]);
        return;
    }

    // ---- self-GEMM
    const int bx = blockIdx.x - 2048;
    const int n0 = (bx % NBX) * 64, m0 = (bx / NBX) * BM;
    const int wm = (wave >> 1) * (BM / 2), wn = (wave & 1) * 32;
    const int r16 = lane & 15, kb = lane >> 4;

    f32x4 acc[MI][NJ];
#pragma unroll
    for (int i = 0; i < MI; ++i)
#pragma unroll
        for (int j = 0; j < NJ; ++j) acc[i][j] = (f32x4)(0.f);

    for (int k0 = 0; k0 < DIN; k0 += 128) {
        if constexpr (A1F32) {
            const float* A = (const float*)Av;
#pragma unroll
            for (int rep = 0; rep < BM / 8; ++rep) {
                int id = rep * 256 + tid;
                int row = id >> 5, c = id & 31;
                float4 f = *(const float4*)&A[(size_t)(m0 + row) * DIN + k0 + c * 4];
                uint2 o; o.x = pack2(f.x, f.y); o.y = pack2(f.z, f.w);
                *(uint2*)&As[row * AWK + c * 4] = o;
            }
        } else {
            const ushort* A = (const ushort*)Av;
#pragma unroll
            for (int rep = 0; rep < BM / 16; ++rep) {
                int id = rep * 256 + tid;
                int row = id >> 4, c = id & 15;
                *(bf16x8*)&As[row * AWK + c * 8] =
                    *(const bf16x8*)&A[(size_t)(m0 + row) * DIN + k0 + c * 8];
            }
        }
#pragma unroll
        for (int rep = 0; rep < 4; ++rep) {
            int id = rep * 256 + tid;
            int row = id >> 4, c = id & 15;
            *(bf16x8*)&Bs[row * AWK + c * 8] =
                *(const bf16x8*)&WsT[(size_t)(n0 + row) * DIN + k0 + c * 8];
        }
        __syncthreads();
#pragma unroll
        for (int kc = 0; kc < 4; ++kc) {
            bf16x8 a[MI], b[NJ];
#pragma unroll
            for (int i = 0; i < MI; ++i)
                a[i] = *(const bf16x8*)&As[(wm + 16 * i + r16) * AWK + kc * 32 + kb * 8];
#pragma unroll
            for (int j = 0; j < NJ; ++j)
                b[j] = *(const bf16x8*)&Bs[(wn + 16 * j + r16) * AWK + kc * 32 + kb * 8];
#pragma unroll
            for (int i = 0; i < MI; ++i)
#pragma unroll
                for (int j = 0; j < NJ; ++j)
                    acc[i][j] = __builtin_amdgcn_mfma_f32_16x16x32_bf16(a[i], b[j], acc[i][j], 0, 0, 0);
        }
        __syncthreads();
    }

#pragma unroll
    for (int i = 0; i < MI; ++i) {
#pragma unroll
        for (int j = 0; j < NJ; ++j) {
            int col = n0 + wn + 16 * j + r16;
            float bv = bias[col];
#pragma unroll
            for (int r = 0; r < 4; ++r) {
                int row = m0 + wm + 16 * i + kb * 4 + r;
                Cself[(size_t)row * DOUT + col] = f2b(acc[i][j][r] + bv);
            }
        }
    }
}

// ---------------------------------------------------------------------------
// adj = H @ H^T, H [8192][64] bf16, C fp32. 128x128 tile, K=64 single stage.
// ---------------------------------------------------------------------------
__global__ __launch_bounds__(256) void aat_k(const ushort* __restrict__ H,
                                             float* __restrict__ C) {
    __shared__ __align__(16) ushort As[128 * 72];
    __shared__ __align__(16) ushort Bs[128 * 72];
    int tid = threadIdx.x, lane = tid & 63, wave = tid >> 6;
    int wm = (wave >> 1) * 64, wn = (wave & 1) * 64;
    int r16 = lane & 15, kb = lane >> 4;
    int m0 = blockIdx.y * 128, n0 = blockIdx.x * 128;

#pragma unroll
    for (int rep = 0; rep < 4; ++rep) {
        int id = rep * 256 + tid;
        int row = id >> 3, c = id & 7;
        *(bf16x8*)&As[row * 72 + c * 8] = *(const bf16x8*)&H[(size_t)(m0 + row) * 64 + c * 8];
        *(bf16x8*)&Bs[row * 72 + c * 8] = *(const bf16x8*)&H[(size_t)(n0 + row) * 64 + c * 8];
    }
    __syncthreads();

    f32x4 acc[4][4];
#pragma unroll
    for (int i = 0; i < 4; ++i)
#pragma unroll
        for (int j = 0; j < 4; ++j) acc[i][j] = (f32x4)(0.f);

#pragma unroll
    for (int kc = 0; kc < 2; ++kc) {
        bf16x8 a[4], b[4];
#pragma unroll
        for (int i = 0; i < 4; ++i)
            a[i] = *(const bf16x8*)&As[(wm + 16 * i + r16) * 72 + kc * 32 + kb * 8];
#pragma unroll
        for (int j = 0; j < 4; ++j)
            b[j] = *(const bf16x8*)&Bs[(wn + 16 * j + r16) * 72 + kc * 32 + kb * 8];
#pragma unroll
        for (int i = 0; i < 4; ++i)
#pragma unroll
            for (int j = 0; j < 4; ++j)
                acc[i][j] = __builtin_amdgcn_mfma_f32_16x16x32_bf16(a[i], b[j], acc[i][j], 0, 0, 0);
    }

#pragma unroll
    for (int i = 0; i < 4; ++i) {
#pragma unroll
        for (int j = 0; j < 4; ++j) {
            int col = n0 + wn + 16 * j + r16;
#pragma unroll
            for (int r = 0; r < 4; ++r) {
                size_t row = m0 + wm + 16 * i + kb * 4 + r;
                C[row * NN + col] = acc[i][j][r];
            }
        }
    }
}

// ---------------------------------------------------------------------------
extern "C" void kernel_launch(void* const* d_in, const int* in_sizes, int n_in,
                              void* d_out, int out_size, void* d_ws, size_t ws_size,
                              hipStream_t stream) {
    const float* feat = (const float*)d_in[0];
    const int* src = (const int*)d_in[1];
    const int* dst = (const int*)d_in[2];
    const float* ew = (const float*)d_in[3];
    const float* Wp1 = (const float*)d_in[5];
    const float* bp1 = (const float*)d_in[6];
    const float* Ws1 = (const float*)d_in[7];
    const float* Wn1 = (const float*)d_in[8];
    const float* b1  = (const float*)d_in[9];
    const float* Wp2 = (const float*)d_in[10];
    const float* bp2 = (const float*)d_in[11];
    const float* Ws2 = (const float*)d_in[12];
    const float* Wn2 = (const float*)d_in[13];
    const float* b2  = (const float*)d_in[14];
    const float* Wp3 = (const float*)d_in[15];
    const float* bp3 = (const float*)d_in[16];
    const float* Ws3 = (const float*)d_in[17];
    const float* Wn3 = (const float*)d_in[18];
    const float* b3  = (const float*)d_in[19];

    float* out = (float*)d_out;          // hd fp32 [8192][64]
    float* adj = out + (size_t)NN * 64;  // adj fp32 [8192][8192]

    char* ws = (char*)d_ws;
    int* cnt      = (int*)(ws + 0x0);          // 32 KB
    uint2* slots  = (uint2*)(ws + 0x10000);    // 6 MB
    ushort* Wp1T = (ushort*)(ws + 0x620000);
    ushort* Ws1T = (ushort*)(ws + 0x628000);
    ushort* Wn1T = (ushort*)(ws + 0x638000);
    ushort* Wp2T = (ushort*)(ws + 0x648000);
    ushort* Ws2T = (ushort*)(ws + 0x668000);
    ushort* Wn2T = (ushort*)(ws + 0x688000);
    ushort* Wp3T = (ushort*)(ws + 0x6A8000);
    ushort* Ws3T = (ushort*)(ws + 0x6C8000);
    ushort* Wn3T = (ushort*)(ws + 0x6D0000);
    ushort* P  = (ushort*)(ws + 0x700000);     // pool bf16 [N][<=256]
    ushort* G  = (ushort*)(ws + 0xB00000);     // agg bf16 [N][<=256]
    ushort* X  = (ushort*)(ws + 0xF00000);     // x2 bf16 [N][256]
    ushort* Y  = (ushort*)(ws + 0x1300000);    // x3 bf16 [N][256]
    ushort* Cs = (ushort*)(ws + 0x1700000);    // self bf16 [N][<=256]
    ushort* hdb = (ushort*)(ws + 0x1B00000);   // hd bf16 [N][64]

    hipMemsetAsync(cnt, 0, NN * sizeof(int), stream);

    // prep: scatter || weight transposes
    PrepArgs pa;
    pa.src = src; pa.dst = dst; pa.ew = ew; pa.cnt = cnt; pa.slots = slots;
    const float* wsrc[9] = {Wp1, Ws1, Wn1, Wp2, Ws2, Wn2, Wp3, Ws3, Wn3};
    ushort* wdst[9] = {Wp1T, Ws1T, Wn1T, Wp2T, Ws2T, Wn2T, Wp3T, Ws3T, Wn3T};
    for (int i = 0; i < 9; ++i) { pa.w[i] = wsrc[i]; pa.wt[i] = wdst[i]; }
    prep_scatter_k<<<1024 + 1472, 256, 0, stream>>>(pa);

    // layer 1 (128 -> 256), A = feat (f32)
    gemm_k<64, 64, true, true, 0, false><<<dim3(2, 128), 256, 0, stream>>>(
        feat, Wp1T, 128, bp1, nullptr, nullptr, P, 128);              // pool1 -> P
    seg_self_k<128, 256, true><<<2048 + 512, 256, 0, stream>>>(
        P, cnt, slots, G, feat, Ws1T, b1, Cs);                        // G, Cself
    gemm_k<64, 64, false, true, 0, true><<<dim3(4, 128), 256, 0, stream>>>(
        G, Wn1T, 128, nullptr, Cs, nullptr, X, 256);                  // X = relu(G@Wn1 + Cs)

    // layer 2 (256 -> 256)
    gemm_k<64, 64, false, true, 0, false><<<dim3(4, 128), 256, 0, stream>>>(
        X, Wp2T, 256, bp2, nullptr, nullptr, P, 256);                 // pool2 -> P
    seg_self_k<256, 256, false><<<2048 + 512, 256, 0, stream>>>(
        P, cnt, slots, G, X, Ws2T, b2, Cs);
    gemm_k<64, 64, false, true, 0, true><<<dim3(4, 128), 256, 0, stream>>>(
        G, Wn2T, 256, nullptr, Cs, nullptr, Y, 256);                  // Y

    // layer 3 (256 -> 64)
    gemm_k<64, 64, false, true, 0, false><<<dim3(4, 128), 256, 0, stream>>>(
        Y, Wp3T, 256, bp3, nullptr, nullptr, P, 256);                 // pool3 -> P
    seg_self_k<256, 64, false><<<2048 + 256, 256, 0, stream>>>(
        P, cnt, slots, G, Y, Ws3T, b3, Cs);
    gemm_k<32, 64, false, true, 2, true><<<dim3(1, 256), 256, 0, stream>>>(
        G, Wn3T, 256, nullptr, Cs, out, hdb, 64);                     // hd fp32 + bf16

    // adj = hd @ hd^T
    aat_k<<<dim3(NN / 128, NN / 128), 256, 0, stream>>>(hdb, adj);
}